// Round 13
// baseline (291.769 us; speedup 1.0000x reference)
//
#include <hip/hip_runtime.h>

// FrameTransformer forward on MI355X.
// Dims: B=2, CH=8, BINS=1024, W=1024, FF=2048, BANDS=4, HD=256, T=B*W=2048.
// bf16 residual stream; single-barrier pipelined GEMMs (48KB LDS, 3 blocks/CU).
// Round 13: softmax fused into AV GEMM (P panel in LDS, XOR-swizzled).

typedef float f32x4 __attribute__((ext_vector_type(4)));
typedef short short8 __attribute__((ext_vector_type(8)));
typedef unsigned short u16;
typedef unsigned int u32;

__device__ __forceinline__ float bf2f(u16 u){
  u32 v = ((u32)u) << 16;
  return __builtin_bit_cast(float, v);
}
__device__ __forceinline__ u16 f2bf(float f){
  u32 u = __builtin_bit_cast(u32, f);
  u32 r = (u + 0x7fffu + ((u >> 16) & 1u)) >> 16;   // RNE
  return (u16)r;
}
__device__ __forceinline__ u32 pack2(float a, float b){
  return (u32)f2bf(a) | ((u32)f2bf(b) << 16);
}
__device__ __forceinline__ void unpack8(uint4 u, float* f){
  f[0]=bf2f(u.x & 0xffffu); f[1]=bf2f(u.x >> 16);
  f[2]=bf2f(u.y & 0xffffu); f[3]=bf2f(u.y >> 16);
  f[4]=bf2f(u.z & 0xffffu); f[5]=bf2f(u.z >> 16);
  f[6]=bf2f(u.w & 0xffffu); f[7]=bf2f(u.w >> 16);
}

// async global->LDS, 16 bytes per lane
__device__ __forceinline__ void gload16(const u16* g, u16* l){
  __builtin_amdgcn_global_load_lds(
      (const __attribute__((address_space(1))) unsigned int*)g,
      (__attribute__((address_space(3))) unsigned int*)l, 16, 0, 0);
}
template<int N> __device__ __forceinline__ void waitvm(){
  asm volatile("s_waitcnt vmcnt(%0)" :: "n"(N) : "memory");
}
__device__ __forceinline__ void barrier(){ __builtin_amdgcn_s_barrier(); }

// ---------------------------------------------------------------- GEMM core
template<int ACT, int OB, int MR, int NR, int DUAL, int NBUF, int RB, int SC>
__device__ __forceinline__
void gemm_body(u16* ldsA, u16* ldsB,
               const u16* Az, const u16* Bz,
               const u16* A2, const u16* B2z,
               float* CfZ, u16* CbZ,
               const float* bias, const void* rz,
               int K, int K2, int lda, int ldb, int lda2, int ldb2, int ldc,
               int apad, int aoff, int m0, int n0)
{
  constexpr int BM = 32 * MR, BN = 32 * NR;
  constexpr int LPT = MR + NR;          // gload16 per thread per tile
  constexpr int PRE = NBUF - 1;
  const int tid = threadIdx.x;
  const int lane = tid & 63, wid = tid >> 6;
  const int wm = wid >> 1, wn = wid & 1;
  const int lr = lane & 15, lk = lane >> 4;
  const int kA = K >> 6;
  const int NT = kA + (DUAL ? (K2 >> 6) : 0);

  auto stage = [&](int buf, int s){
    #pragma unroll
    for (int i = 0; i < MR; i++){
      int ch = tid + i * 256;
      int r = ch >> 3, c = ch & 7;
      int csw = (c ^ (r & 7)) * 8;
      const u16* src;
      bool d2 = DUAL && (s >= kA);
      if (d2){
        src = A2 + (long)(m0 + r) * lda2 + (s - kA) * 64 + csw;
      } else {
        int gm = m0 + r;
        long ar = (long)gm + (long)(gm >> 10) * apad + aoff;
        src = Az + ar * lda + s * 64 + csw;
      }
      gload16(src, ldsA + buf * (BM * 64) + ch * 8);
    }
    #pragma unroll
    for (int i = 0; i < NR; i++){
      int ch = tid + i * 256;
      int r = ch >> 3, c = ch & 7;
      int csw = (c ^ (r & 7)) * 8;
      const u16* src;
      bool d2 = DUAL && (s >= kA);
      if (d2) src = B2z + (long)(n0 + r) * ldb2 + (s - kA) * 64 + csw;
      else    src = Bz  + (long)(n0 + r) * ldb  + s * 64 + csw;
      gload16(src, ldsB + buf * (BN * 64) + ch * 8);
    }
  };

  f32x4 acc[MR][NR];
  #pragma unroll
  for (int i = 0; i < MR; i++)
    #pragma unroll
    for (int j = 0; j < NR; j++) acc[i][j] = f32x4{0.f, 0.f, 0.f, 0.f};

  auto compute = [&](int cur){
    const u16* Ab = ldsA + cur * (BM * 64);
    const u16* Bb = ldsB + cur * (BN * 64);
    short8 av[2][MR], bv[2][NR];
    #pragma unroll
    for (int h = 0; h < 2; h++){
      int g = h * 4 + lk;
      #pragma unroll
      for (int i = 0; i < MR; i++){
        int row = wm * 16 * MR + i * 16 + lr;
        av[h][i] = *(const short8*)(Ab + row * 64 + ((g ^ (row & 7)) * 8));
      }
      #pragma unroll
      for (int j = 0; j < NR; j++){
        int row = wn * 16 * NR + j * 16 + lr;
        bv[h][j] = *(const short8*)(Bb + row * 64 + ((g ^ (row & 7)) * 8));
      }
    }
    #pragma unroll
    for (int h = 0; h < 2; h++)
      #pragma unroll
      for (int i = 0; i < MR; i++)
        #pragma unroll
        for (int j = 0; j < NR; j++)
          acc[i][j] = __builtin_amdgcn_mfma_f32_16x16x32_bf16(av[h][i], bv[h][j], acc[i][j], 0, 0, 0);
  };

  const int npre = NT < PRE ? NT : PRE;
  for (int p = 0; p < npre; p++) stage(p, p);
  int s = 0;
  for (; s < NT - PRE; s++){
    waitvm<(NBUF - 2) * LPT>();
    barrier();
    stage((s + PRE) % NBUF, s + PRE);
    compute(s % NBUF);
  }
  for (; s < NT; s++){
    waitvm<0>();
    barrier();
    compute(s % NBUF);
  }

  const float* rzf = (!RB) ? (const float*)rz : nullptr;
  const u16*  rzb = ( RB) ? (const u16*)rz  : nullptr;
  #pragma unroll
  for (int i = 0; i < MR; i++){
    int rowb = m0 + wm * 16 * MR + i * 16 + lk * 4;   // D: row=(lane>>4)*4+r
    #pragma unroll
    for (int j = 0; j < NR; j++){
      int colg = n0 + wn * 16 * NR + j * 16 + lr;     // D: col=lane&15
      f32x4 v = acc[i][j];
      float bvl = bias ? bias[colg] : 0.f;
      #pragma unroll
      for (int r = 0; r < 4; r++){
        long idx = (long)(rowb + r) * ldc + colg;
        float xv = v[r] + bvl;
        if constexpr (ACT == 1){ xv = fmaxf(xv, 0.f); }
        if constexpr (ACT == 2){ xv = fmaxf(xv, 0.f); xv = xv * xv; }
        if constexpr (SC){ xv *= 0.03125f; }
        if constexpr (RB){ if (rzb) xv += bf2f(rzb[idx]); }
        else             { if (rzf) xv += rzf[idx]; }
        if constexpr (OB) CbZ[idx] = f2bf(xv); else CfZ[idx] = xv;
      }
    }
  }
}

// ---------------------------------------------------------------- GEMM wrapper
template<int ACT, int OB, int MR, int NR, int DUAL, int NBUF, int RB, int SC>
__global__ __launch_bounds__(256)
void gemm_bt(const u16* __restrict__ A, const u16* __restrict__ Bw,
             const u16* __restrict__ A2, const u16* __restrict__ B2,
             float* __restrict__ Cf, u16* __restrict__ Cb,
             const float* __restrict__ bias, const void* __restrict__ resid,
             int M, int N, int K, int K2,
             int lda, int ldb, int lda2, int ldb2, int ldc,
             int apad, int aoff,
             long aZHi, long aZLo, long bZHi, long bZLo,
             long b2ZHi, long b2ZLo, long cZHi, long cZLo)
{
  constexpr int BM = 32 * MR, BN = 32 * NR;
  __shared__ __align__(16) u16 As[NBUF * BM * 64];
  __shared__ __align__(16) u16 Bs[NBUF * BN * 64];
  const int z = blockIdx.z, zh = z >> 2, zl = z & 3;
  const u16* Az = A + zh * aZHi + zl * aZLo;
  const u16* Bz = Bw + zh * bZHi + zl * bZLo;
  const u16* B2z = DUAL ? (B2 + zh * b2ZHi + zl * b2ZLo) : nullptr;
  const long coff = (long)zh * cZHi + (long)zl * cZLo;
  const int m0 = blockIdx.y * BM, n0 = blockIdx.x * BN;
  float* CfZ = Cf ? Cf + coff : nullptr;
  u16*  CbZ = Cb ? Cb + coff : nullptr;
  const void* rz = nullptr;
  if (resid) rz = RB ? (const void*)(((const u16*)resid) + coff)
                     : (const void*)(((const float*)resid) + coff);
  gemm_body<ACT,OB,MR,NR,DUAL,NBUF,RB,SC>(As, Bs, Az, Bz, A2, B2z, CfZ, CbZ,
      bias, rz, K, K2, lda, ldb, lda2, ldb2, ldc, apad, aoff, m0, n0);
}

// ---------------------------------------------------------------- fused c1L||c1R
__global__ __launch_bounds__(256)
void gemm_c1(const u16* __restrict__ HPAD, const u16* __restrict__ wbL,
             const u16* __restrict__ wbR, u16* __restrict__ HS, u16* __restrict__ HR)
{
  __shared__ __align__(16) u16 lds[24576];   // 48KB
  const int bid = blockIdx.x;
  if (bid < 512){
    const int n0 = (bid & 31) * 64, m0 = (bid >> 5) * 128;
    gemm_body<1,1,4,2,0,2,0,0>(lds, lds + 2 * 128 * 64,
        HPAD, wbL, nullptr, nullptr, nullptr, HS, nullptr, nullptr,
        1024, 0, 1024, 1024, 0, 0, 2048, 2, 1, m0, n0);
  } else {
    const int r = bid - 512;
    const int n0 = (r & 15) * 32, m0 = (r >> 4) * 64;
    gemm_body<1,1,2,1,0,4,0,0>(lds, lds + 4 * 64 * 64,
        HPAD, wbR, nullptr, nullptr, nullptr, HR, nullptr, nullptr,
        3072, 0, 1024, 3072, 0, 0, 512, 2, 0, m0, n0);
  }
}

// ---------------------------------------------------------------- fused GLU GEMM
template<int NBUF>
__global__ __launch_bounds__(256)
void gemm_glu(const u16* __restrict__ A, const u16* __restrict__ Bw,
              u16* __restrict__ XF)
{
  constexpr int LPT = 6;
  constexpr int PRE = NBUF - 1;
  constexpr int NT = 16;
  __shared__ __align__(16) u16 As[NBUF][64 * 64];
  __shared__ __align__(16) u16 Bs[NBUF][128 * 64];
  const int tid = threadIdx.x;
  const int m0 = blockIdx.y * 64, n0 = blockIdx.x * 64;
  const int lane = tid & 63, wid = tid >> 6;
  const int wm = wid >> 1, wn = wid & 1;
  const int lr = lane & 15, lk = lane >> 4;

  auto stage = [&](int buf, int s){
    #pragma unroll
    for (int i = 0; i < 2; i++){
      int ch = tid + i * 256;
      int r = ch >> 3, c = ch & 7;
      int csw = (c ^ (r & 7)) * 8;
      gload16(A + (long)(m0 + r) * 1024 + s * 64 + csw, &As[buf][ch * 8]);
    }
    #pragma unroll
    for (int i = 0; i < 4; i++){
      int ch = tid + i * 256;
      int r = ch >> 3, c = ch & 7;
      int csw = (c ^ (r & 7)) * 8;
      int grow = (r < 64) ? (n0 + r) : (1024 + n0 + r - 64);
      gload16(Bw + (long)grow * 1024 + s * 64 + csw, &Bs[buf][ch * 8]);
    }
  };

  f32x4 accv[2][2], accg[2][2];
  #pragma unroll
  for (int i = 0; i < 2; i++)
    #pragma unroll
    for (int j = 0; j < 2; j++){
      accv[i][j] = f32x4{0.f,0.f,0.f,0.f};
      accg[i][j] = f32x4{0.f,0.f,0.f,0.f};
    }

  auto compute = [&](int cur){
    const u16* Ab = &As[cur][0];
    const u16* Bb = &Bs[cur][0];
    short8 av[2][2], bvv[2][2], bvg[2][2];
    #pragma unroll
    for (int h = 0; h < 2; h++){
      int g = h * 4 + lk;
      #pragma unroll
      for (int i = 0; i < 2; i++){
        int row = wm * 32 + i * 16 + lr;
        av[h][i] = *(const short8*)(Ab + row * 64 + ((g ^ (row & 7)) * 8));
      }
      #pragma unroll
      for (int j = 0; j < 2; j++){
        int row = wn * 32 + j * 16 + lr;
        bvv[h][j] = *(const short8*)(Bb + row * 64 + ((g ^ (row & 7)) * 8));
        int rowg = 64 + row;
        bvg[h][j] = *(const short8*)(Bb + rowg * 64 + ((g ^ (rowg & 7)) * 8));
      }
    }
    #pragma unroll
    for (int h = 0; h < 2; h++)
      #pragma unroll
      for (int i = 0; i < 2; i++)
        #pragma unroll
        for (int j = 0; j < 2; j++){
          accv[i][j] = __builtin_amdgcn_mfma_f32_16x16x32_bf16(av[h][i], bvv[h][j], accv[i][j], 0, 0, 0);
          accg[i][j] = __builtin_amdgcn_mfma_f32_16x16x32_bf16(av[h][i], bvg[h][j], accg[i][j], 0, 0, 0);
        }
  };

  const int npre = NT < PRE ? NT : PRE;
  for (int p = 0; p < npre; p++) stage(p, p);
  int s = 0;
  for (; s < NT - PRE; s++){
    waitvm<(NBUF - 2) * LPT>();
    barrier();
    stage((s + PRE) % NBUF, s + PRE);
    compute(s % NBUF);
  }
  for (; s < NT; s++){
    waitvm<0>();
    barrier();
    compute(s % NBUF);
  }

  #pragma unroll
  for (int i = 0; i < 2; i++){
    int rowb = m0 + wm * 32 + i * 16 + lk * 4;
    #pragma unroll
    for (int j = 0; j < 2; j++){
      int colg = n0 + wn * 32 + j * 16 + lr;
      #pragma unroll
      for (int r = 0; r < 4; r++){
        long idx = (long)(rowb + r) * 1024 + colg;
        float g = accg[i][j][r];
        float nv = bf2f(XF[idx]) + accv[i][j][r] / (1.f + __expf(-g));
        XF[idx] = f2bf(nv);
      }
    }
  }
}

// ---------------------------------------------------------------- fused softmax + AV
// Per block: z = blockIdx.z, 32 q-rows (blockIdx.y), 64 h-cols (blockIdx.x).
// 1) gload_lds the raw 32x1024 bf16 score rows (linear).
// 2) wave-parallel softmax in LDS (fp32 math), write back XOR-swizzled
//    (16B chunk index ^= row&7) for conflict-light MFMA frag reads.
// 3) K-loop: A-frags from resident P panel, V streamed via 2-deep ring.
__global__ __launch_bounds__(256)
void fused_av(const u16* __restrict__ S, const u16* __restrict__ V,
              u16* __restrict__ O)
{
  __shared__ __align__(16) u16 P[32 * 1024];     // 64KB
  __shared__ __align__(16) u16 Bs[2][64 * 64];   // 16KB
  const int z = blockIdx.z;
  const int m0 = blockIdx.y * 32;
  const int n0 = blockIdx.x * 64;
  const int tid = threadIdx.x;
  const int lane = tid & 63, wid = tid >> 6;
  const int wm = wid >> 1, wn = wid & 1;
  const int lr = lane & 15, lk = lane >> 4;
  const u16* Sz = S + (long)z * 1048576 + (long)m0 * 1024;
  const u16* Vz = V + (long)z * 262144;          // v2T [8][256][1024]

  auto stageB = [&](int buf, int s){
    #pragma unroll
    for (int i = 0; i < 2; i++){
      int ch = tid + i * 256;
      int r = ch >> 3, c = ch & 7;
      int csw = (c ^ (r & 7)) * 8;
      gload16(Vz + (long)(n0 + r) * 1024 + s * 64 + csw, &Bs[buf][ch * 8]);
    }
  };

  // A panel (16 chunks/thread) then B tile 0
  #pragma unroll
  for (int i = 0; i < 16; i++){
    int ch = tid + i * 256;
    gload16(Sz + ch * 8, &P[ch * 8]);
  }
  stageB(0, 0);
  waitvm<2>();          // A done; B0 may still fly
  barrier();

  // softmax: wave wid owns rows wid*8 .. wid*8+7; all 64 lanes per row
  #pragma unroll
  for (int i = 0; i < 8; i++){
    int row = wid * 8 + i;
    const u16* pr = &P[row * 1024 + lane * 16];
    uint4 a = *(const uint4*)pr;
    uint4 b = *(const uint4*)(pr + 8);
    float v[16];
    unpack8(a, v); unpack8(b, v + 8);
    float m = v[0];
    #pragma unroll
    for (int j = 1; j < 16; j++) m = fmaxf(m, v[j]);
    #pragma unroll
    for (int o = 32; o; o >>= 1) m = fmaxf(m, __shfl_xor(m, o));
    float sm = 0.f;
    #pragma unroll
    for (int j = 0; j < 16; j++){ v[j] = __expf(v[j] - m); sm += v[j]; }
    #pragma unroll
    for (int o = 32; o; o >>= 1) sm += __shfl_xor(sm, o);
    const float inv = 1.f / sm;
    u32 w[8];
    #pragma unroll
    for (int j = 0; j < 16; j += 2) w[j / 2] = pack2(v[j] * inv, v[j + 1] * inv);
    const int x = row & 7;
    const int cc = lane * 2;
    *(uint4*)&P[row * 1024 + ((cc       ^ x)) * 8] = *(uint4*)&w[0];
    *(uint4*)&P[row * 1024 + (((cc + 1) ^ x)) * 8] = *(uint4*)&w[4];
  }
  barrier();

  f32x4 acc[2];
  acc[0] = f32x4{0.f,0.f,0.f,0.f};
  acc[1] = f32x4{0.f,0.f,0.f,0.f};
  for (int s = 0; s < 16; s++){
    waitvm<0>();
    barrier();
    if (s + 1 < 16) stageB((s + 1) & 1, s + 1);
    const u16* Bb = &Bs[s & 1][0];
    const int arow = wm * 16 + lr;
    #pragma unroll
    for (int h = 0; h < 2; h++){
      int g = h * 4 + lk;
      short8 av = *(const short8*)&P[arow * 1024 + s * 64 + ((g ^ (arow & 7)) * 8)];
      #pragma unroll
      for (int j = 0; j < 2; j++){
        int brow = wn * 32 + j * 16 + lr;
        short8 bv = *(const short8*)(Bb + brow * 64 + ((g ^ (brow & 7)) * 8));
        acc[j] = __builtin_amdgcn_mfma_f32_16x16x32_bf16(av, bv, acc[j], 0, 0, 0);
      }
    }
  }

  const int rowb = (z >> 2) * 1024 + m0 + wm * 16 + lk * 4;
  #pragma unroll
  for (int j = 0; j < 2; j++){
    int colg = (z & 3) * 256 + n0 + wn * 32 + j * 16 + lr;
    #pragma unroll
    for (int r = 0; r < 4; r++)
      O[(long)(rowb + r) * 1024 + colg] = f2bf(acc[j][r]);
  }
}

// ---------------------------------------------------------------- LayerNorm
template<int NC, int INBF, int ADDHR>
__global__ __launch_bounds__(256)
void ln_kernel(const void* __restrict__ in, u16* __restrict__ out,
               const float* __restrict__ gg, const float* __restrict__ bb,
               int rowpad, int rowadd, const u16* __restrict__ addp)
{
  constexpr int PER = NC / 256;
  const int row = blockIdx.x;
  const int tid = threadIdx.x;
  float v[PER];
  if constexpr (INBF){
    const u16* x = ((const u16*)in) + (long)row * NC + tid * PER;
    if constexpr (PER == 4){
      uint2 u = *(const uint2*)x;
      v[0]=bf2f(u.x & 0xffffu); v[1]=bf2f(u.x >> 16);
      v[2]=bf2f(u.y & 0xffffu); v[3]=bf2f(u.y >> 16);
    } else {
      #pragma unroll
      for (int i = 0; i < PER; i += 8){
        uint4 u = *(const uint4*)(x + i);
        unpack8(u, &v[i]);
      }
    }
  } else {
    const float* x = ((const float*)in) + (long)row * NC + tid * PER;
    #pragma unroll
    for (int i = 0; i < PER; i += 4){
      f32x4 t = *(const f32x4*)(x + i);
      v[i] = t.x; v[i+1] = t.y; v[i+2] = t.z; v[i+3] = t.w;
    }
  }
  if constexpr (ADDHR){
    const int c0i = tid * PER;            // PER==8 here
    if (c0i < 512){
      uint4 u = *(const uint4*)(addp + (long)row * 512 + c0i);
      float a8[8]; unpack8(u, a8);
      #pragma unroll
      for (int i = 0; i < 8; i++) v[i] += a8[i];
    }
  }
  float s = 0.f, sq = 0.f;
  #pragma unroll
  for (int i = 0; i < PER; i++){ s += v[i]; sq += v[i] * v[i]; }
  #pragma unroll
  for (int o = 32; o; o >>= 1){ s += __shfl_xor(s, o); sq += __shfl_xor(sq, o); }
  __shared__ float as_[4], aq_[4];
  const int wv = tid >> 6;
  if ((tid & 63) == 0){ as_[wv] = s; aq_[wv] = sq; }
  __syncthreads();
  s  = as_[0] + as_[1] + as_[2] + as_[3];
  sq = aq_[0] + aq_[1] + aq_[2] + aq_[3];
  const float mean = s * (1.f / NC);
  const float var  = sq * (1.f / NC) - mean * mean;
  const float rs = rsqrtf(var + 1e-5f);
  const long orow = (long)row + (long)(row >> 10) * rowpad + rowadd;
  u16* op = out + orow * NC + tid * PER;
  u32 word[PER / 2];
  #pragma unroll
  for (int i = 0; i < PER; i += 2){
    int c = tid * PER + i;
    float y0 = (v[i]   - mean) * rs * gg[c]   + bb[c];
    float y1 = (v[i+1] - mean) * rs * gg[c+1] + bb[c+1];
    word[i / 2] = pack2(y0, y1);
  }
  if constexpr (PER == 4) *(uint2*)op = *(uint2*)word;
  else                    *(uint4*)op = *(uint4*)word;
}

// ---------------------------------------------------------------- small kernels
// XF bf16 [b*1024+w][f] -> out fp32 [b][1][f][w]
__global__ __launch_bounds__(256)
void tr_out_kernel(const u16* __restrict__ xf, float* __restrict__ out)
{
  __shared__ float tile[32][33];
  const int b = blockIdx.z, f0 = blockIdx.x * 32, w0 = blockIdx.y * 32;
  const int tx = threadIdx.x, ty = threadIdx.y;
  #pragma unroll
  for (int i = 0; i < 4; i++)
    tile[ty + i * 8][tx] = bf2f(xf[((long)(b * 1024 + w0 + ty + i * 8)) * 1024 + f0 + tx]);
  __syncthreads();
  #pragma unroll
  for (int i = 0; i < 4; i++)
    out[((long)(b * 1024 + f0 + ty + i * 8)) * 1024 + w0 + tx] = tile[tx][ty + i * 8];
}

// depthwise conv k=9: dwT[9][2048]; 8ch x 4tok per thread, sliding window.
__global__ __launch_bounds__(256)
void dwconv9_kernel(const u16* __restrict__ in, u16* __restrict__ out,
                    const float* __restrict__ dwT)
{
  const int id = blockIdx.x * 256 + threadIdx.x;   // 512 blocks
  const int cg = id & 255;
  const int tg = id >> 8;
  const int c0 = cg * 8;
  const int t0 = tg * 4;
  const int b = t0 >> 10;
  const int w0 = t0 & 1023;
  const u16* bin = in + ((long)b << 10) * 2048 + c0;
  float wt[9][8];
  #pragma unroll
  for (int j = 0; j < 9; j++){
    f32x4 lo = *(const f32x4*)(dwT + j * 2048 + c0);
    f32x4 hi = *(const f32x4*)(dwT + j * 2048 + c0 + 4);
    wt[j][0]=lo.x; wt[j][1]=lo.y; wt[j][2]=lo.z; wt[j][3]=lo.w;
    wt[j][4]=hi.x; wt[j][5]=hi.y; wt[j][6]=hi.z; wt[j][7]=hi.w;
  }
  float win[9][8];
  #pragma unroll
  for (int r = 0; r < 9; r++){
    int wr = w0 - 4 + r;
    if (wr >= 0 && wr < 1024){
      uint4 u = *(const uint4*)(bin + (long)wr * 2048);
      unpack8(u, win[r]);
    } else {
      #pragma unroll
      for (int i = 0; i < 8; i++) win[r][i] = 0.f;
    }
  }
  #pragma unroll
  for (int s = 0; s < 4; s++){
    float acc[8] = {0,0,0,0,0,0,0,0};
    #pragma unroll
    for (int j = 0; j < 9; j++)
      #pragma unroll
      for (int i = 0; i < 8; i++)
        acc[i] += win[(s + j) % 9][i] * wt[j][i];
    uint4 o;
    o.x = pack2(acc[0], acc[1]); o.y = pack2(acc[2], acc[3]);
    o.z = pack2(acc[4], acc[5]); o.w = pack2(acc[6], acc[7]);
    *(uint4*)(out + (long)(t0 + s) * 2048 + c0) = o;
    if (s < 3){
      int wr = w0 + s + 5;
      if (wr < 1024){
        uint4 u = *(const uint4*)(bin + (long)wr * 2048);
        unpack8(u, win[s % 9]);
      } else {
        #pragma unroll
        for (int i = 0; i < 8; i++) win[s % 9][i] = 0.f;
      }
    }
  }
}

// merged q/k depthwise conv3 (bid<512) + v conv3-transpose (bid>=512)
__global__ __launch_bounds__(256)
void qkvconv_kernel(const u16* __restrict__ qkv,
                    u16* __restrict__ q2b, const float* __restrict__ qwT, const float* __restrict__ qbb,
                    u16* __restrict__ k2b, const float* __restrict__ kwT, const float* __restrict__ kbb,
                    u16* __restrict__ v2T, const float* __restrict__ vcw, const float* __restrict__ vcb)
{
  __shared__ float ins[34][33];
  __shared__ float outs[32][33];
  const int bid = blockIdx.x;
  const int tid = threadIdx.x;
  if (bid < 512){
    const int sel = bid >> 8;
    const u16* in  = qkv + sel * 1024;
    u16* out       = sel ? k2b : q2b;
    const float* wT = sel ? kwT : qwT;
    const float* bp = sel ? kbb : qbb;
    const int id = (bid & 255) * 256 + tid;
    const int cg = id & 127;
    const int tg = id >> 7;
    const int c0 = cg * 8;
    const int t0 = tg * 4;
    const int b = t0 >> 10;
    const int w0 = t0 & 1023;
    const u16* bin = in + ((long)b << 10) * 3072 + c0;
    float wt[3][8], bias[8];
    #pragma unroll
    for (int j = 0; j < 3; j++){
      f32x4 lo = *(const f32x4*)(wT + j * 1024 + c0);
      f32x4 hi = *(const f32x4*)(wT + j * 1024 + c0 + 4);
      wt[j][0]=lo.x; wt[j][1]=lo.y; wt[j][2]=lo.z; wt[j][3]=lo.w;
      wt[j][4]=hi.x; wt[j][5]=hi.y; wt[j][6]=hi.z; wt[j][7]=hi.w;
    }
    {
      f32x4 lo = *(const f32x4*)(bp + c0);
      f32x4 hi = *(const f32x4*)(bp + c0 + 4);
      bias[0]=lo.x; bias[1]=lo.y; bias[2]=lo.z; bias[3]=lo.w;
      bias[4]=hi.x; bias[5]=hi.y; bias[6]=hi.z; bias[7]=hi.w;
    }
    float win[3][8];
    #pragma unroll
    for (int r = 0; r < 3; r++){
      int wr = w0 - 1 + r;
      if (wr >= 0 && wr < 1024){
        uint4 u = *(const uint4*)(bin + (long)wr * 3072);
        unpack8(u, win[r]);
      } else {
        #pragma unroll
        for (int i = 0; i < 8; i++) win[r][i] = 0.f;
      }
    }
    #pragma unroll
    for (int s = 0; s < 4; s++){
      float acc[8];
      #pragma unroll
      for (int i = 0; i < 8; i++) acc[i] = bias[i];
      #pragma unroll
      for (int j = 0; j < 3; j++)
        #pragma unroll
        for (int i = 0; i < 8; i++)
          acc[i] += win[(s + j) % 3][i] * wt[j][i];
      uint4 o;
      o.x = pack2(acc[0], acc[1]); o.y = pack2(acc[2], acc[3]);
      o.z = pack2(acc[4], acc[5]); o.w = pack2(acc[6], acc[7]);
      *(uint4*)(out + (long)(t0 + s) * 1024 + c0) = o;
      if (s < 3){
        int wr = w0 + s + 2;
        if (wr < 1024){
          uint4 u = *(const uint4*)(bin + (long)wr * 3072);
          unpack8(u, win[s % 3]);
        } else {
          #pragma unroll
          for (int i = 0; i < 8; i++) win[s % 3][i] = 0.f;
        }
      }
    }
  } else {
    const int vb = bid - 512;                        // 2048 blocks
    const int b = vb >> 10;
    const int rem = vb & 1023;
    const int w0 = (rem & 31) * 32, c0 = (rem >> 5) * 32;
    const int tx = tid & 31, ty = tid >> 5;
    const u16* in = qkv + 2048;
    for (int r = ty; r < 34; r += 8){
      int w = w0 - 1 + r;
      ins[r][tx] = (w >= 0 && w < 1024) ? bf2f(in[((long)(b * 1024 + w)) * 3072 + c0 + tx]) : 0.f;
    }
    __syncthreads();
    const float wt0 = vcw[(c0 + tx) * 3 + 0], wt1 = vcw[(c0 + tx) * 3 + 1], wt2 = vcw[(c0 + tx) * 3 + 2];
    const float bb = vcb[c0 + tx];
    #pragma unroll
    for (int i = 0; i < 4; i++){
      int wl = ty + i * 8;
      outs[wl][tx] = ins[wl][tx] * wt0 + ins[wl + 1][tx] * wt1 + ins[wl + 2][tx] * wt2 + bb;
    }
    __syncthreads();
    #pragma unroll
    for (int i = 0; i < 4; i++){
      int cl = ty + i * 8;
      int c = c0 + cl; int n = c >> 8; int h = c & 255;
      v2T[((long)((b * 4 + n) * 256 + h)) * 1024 + w0 + tx] = f2bf(outs[tx][cl]);
    }
  }
}

// ---------------------------------------------------------------- prep (merged, vectorized)
struct Ptrs9 { const float* s[9]; u16* d[9]; };

__global__ __launch_bounds__(256)
void prep_all_kernel(Ptrs9 p,
                     const float* __restrict__ c1R_w, u16* __restrict__ wb_c1R,
                     const float* __restrict__ er, u16* __restrict__ wb_erT,
                     const float* __restrict__ c1M_dw, float* __restrict__ dwT,
                     const float* __restrict__ qcw, float* __restrict__ qcwT,
                     const float* __restrict__ kcw, float* __restrict__ kcwT,
                     const float* __restrict__ qb, const float* __restrict__ kb,
                     const float* __restrict__ vb, float* __restrict__ bqkv,
                     u16* __restrict__ hpad,
                     const float* __restrict__ x, const float* __restrict__ w_in,
                     u16* __restrict__ XF)
{
  __shared__ float tile[32][33];
  const int tid = threadIdx.x;
  const int bid = blockIdx.x;
  if (bid < 7168){
    int job, base;
    if      (bid < 1024){ job = 0; base = 0; }
    else if (bid < 2048){ job = 1; base = 1024; }
    else if (bid < 3072){ job = 2; base = 2048; }
    else if (bid < 3584){ job = 3; base = 3072; }
    else if (bid < 4096){ job = 4; base = 3584; }
    else if (bid < 4608){ job = 5; base = 4096; }
    else if (bid < 5120){ job = 6; base = 4608; }
    else if (bid < 6144){ job = 7; base = 5120; }
    else                { job = 8; base = 6144; }
    long off = ((long)(bid - base) * 256 + tid) * 8;
    const float* src = p.s[job] + off;
    f32x4 va = *(const f32x4*)src;
    f32x4 vb4 = *(const f32x4*)(src + 4);
    uint4 o;
    o.x = pack2(va.x, va.y); o.y = pack2(va.z, va.w);
    o.z = pack2(vb4.x, vb4.y); o.w = pack2(vb4.z, vb4.w);
    *(uint4*)(p.d[job] + off) = o;
    return;
  }
  const int b2 = bid - 7168;   // 0..4395
  if (b2 < 2048){
    int t = b2 * 256 + tid;
    int oc = t >> 10, ic = t & 1023;
    const float* src = c1R_w + (long)oc * 3072 + ic * 3;
    float r0 = src[0], r1 = src[1], r2 = src[2];
    u16* dst = wb_c1R + (long)oc * 3072 + ic;
    dst[0]    = f2bf(r0);
    dst[1024] = f2bf(r1);
    dst[2048] = f2bf(r2);
  } else if (b2 < 2304){
    int r = b2 - 2048;
    int h0 = (r & 7) * 32, q0 = (r >> 3) * 32;
    int tx = tid & 31, ty = tid >> 5;
    #pragma unroll
    for (int i = 0; i < 4; i++)
      tile[ty + i * 8][tx] = er[(long)(h0 + ty + i * 8) * 1024 + q0 + tx];
    __syncthreads();
    #pragma unroll
    for (int i = 0; i < 4; i++)
      wb_erT[(long)(q0 + ty + i * 8) * 256 + h0 + tx] = f2bf(tile[tx][ty + i * 8]);
  } else if (b2 < 2312){
    int c = (b2 - 2304) * 256 + tid;
    const float* src = c1M_dw + (long)c * 9;
    #pragma unroll
    for (int j = 0; j < 9; j++) dwT[j * 2048 + c] = src[j];
  } else if (b2 < 2316){
    int c = (b2 - 2312) * 256 + tid;
    const float* src = qcw + (long)c * 3;
    #pragma unroll
    for (int j = 0; j < 3; j++) qcwT[j * 1024 + c] = src[j];
  } else if (b2 < 2320){
    int c = (b2 - 2316) * 256 + tid;
    const float* src = kcw + (long)c * 3;
    #pragma unroll
    for (int j = 0; j < 3; j++) kcwT[j * 1024 + c] = src[j];
  } else if (b2 < 2332){
    int id = (b2 - 2320) * 256 + tid;
    bqkv[id] = (id < 1024) ? qb[id] : (id < 2048) ? kb[id - 1024] : vb[id - 2048];
  } else if (b2 < 2348){
    int id = (b2 - 2332) * 256 + tid;
    int r = id >> 10; int c = id & 1023;
    int b = r >> 1; int edge = r & 1;
    long row = (long)b * 1026 + (edge ? 1025 : 0);
    hpad[row * 1024 + c] = 0;
  } else {
    const int vb4 = b2 - 2348;
    const int b = vb4 >> 10;
    const int rem = vb4 & 1023;
    const int f0 = (rem & 31) * 32, w0 = (rem >> 5) * 32;
    const int tx = tid & 7, ty = tid >> 3;
    float wr[8];
    #pragma unroll
    for (int c = 0; c < 8; c++) wr[c] = w_in[c];
    f32x4 acc = f32x4{0.f, 0.f, 0.f, 0.f};
    #pragma unroll
    for (int c = 0; c < 8; c++){
      f32x4 xv = *(const f32x4*)(x + (((long)(b * 8 + c)) * 1024 + f0 + ty) * 1024 + w0 + tx * 4);
      acc += wr[c] * xv;
    }
    tile[ty][tx * 4 + 0] = acc.x;
    tile[ty][tx * 4 + 1] = acc.y;
    tile[ty][tx * 4 + 2] = acc.z;
    tile[ty][tx * 4 + 3] = acc.w;
    __syncthreads();
    const int wl = tid >> 3, fseg = (tid & 7) * 4;
    uint2 o;
    o.x = pack2(tile[fseg + 0][wl], tile[fseg + 1][wl]);
    o.y = pack2(tile[fseg + 2][wl], tile[fseg + 3][wl]);
    *(uint2*)(XF + ((long)(b * 1024 + w0 + wl)) * 1024 + f0 + fseg) = o;
  }
}

// ---------------------------------------------------------------- launch
extern "C" void kernel_launch(void* const* d_in, const int* in_sizes, int n_in,
                              void* d_out, int out_size, void* d_ws, size_t ws_size,
                              hipStream_t stream)
{
  (void)in_sizes; (void)n_in; (void)out_size; (void)ws_size;
  const float* x     = (const float*)d_in[0];
  const float* w_in  = (const float*)d_in[1];
  const float* ln1_g = (const float*)d_in[2];
  const float* ln1_b = (const float*)d_in[3];
  const float* glu_w = (const float*)d_in[4];
  const float* ln2_g = (const float*)d_in[5];
  const float* ln2_b = (const float*)d_in[6];
  const float* c1L_w = (const float*)d_in[7];
  const float* c1R_w = (const float*)d_in[8];
  const float* ln3_g = (const float*)d_in[9];
  const float* ln3_b = (const float*)d_in[10];
  const float* c1M_dw= (const float*)d_in[11];
  const float* c1M_pw= (const float*)d_in[12];
  const float* ln4_g = (const float*)d_in[13];
  const float* ln4_b = (const float*)d_in[14];
  const float* qw  = (const float*)d_in[15];
  const float* qb  = (const float*)d_in[16];
  const float* qcw = (const float*)d_in[17];
  const float* qcb = (const float*)d_in[18];
  const float* kw  = (const float*)d_in[19];
  const float* kb  = (const float*)d_in[20];
  const float* kcw = (const float*)d_in[21];
  const float* kcb = (const float*)d_in[22];
  const float* vw  = (const float*)d_in[23];
  const float* vb  = (const float*)d_in[24];
  const float* vcw = (const float*)d_in[25];
  const float* vcb = (const float*)d_in[26];
  const float* ow  = (const float*)d_in[27];
  const float* ob  = (const float*)d_in[28];
  const float* er  = (const float*)d_in[29];
  const float* ln5_g = (const float*)d_in[30];
  const float* ln5_b = (const float*)d_in[31];
  const float* c2_w  = (const float*)d_in[32];
  const float* c3_w  = (const float*)d_in[33];
  float* out = (float*)d_out;

  const long TT = 2048;   // B*W tokens
  char* wsb = (char*)d_ws;
  size_t off = 0;
  auto alloc = [&](size_t bytes) -> char* {
    char* p = wsb + off;
    off = (off + bytes + 255) & ~(size_t)255;
    return p;
  };
  u16* XF     = (u16*)alloc(TT * 1024 * 2);                // bf16 residual stream
  u16* wb_glu = (u16*)alloc(2048L * 1024 * 2);
  u16* wb_c1L = (u16*)alloc(2048L * 1024 * 2);
  u16* wb_c1R = (u16*)alloc(512L * 3072 * 2);
  u16* wb_pw  = (u16*)alloc(1024L * 2048 * 2);
  u16* wb_q   = (u16*)alloc(1024L * 1024 * 2);             // contiguous with k,v
  u16* wb_k   = (u16*)alloc(1024L * 1024 * 2);
  u16* wb_v   = (u16*)alloc(1024L * 1024 * 2);
  u16* wb_ow  = (u16*)alloc(1024L * 1024 * 2);
  u16* wb_c2  = (u16*)alloc(2048L * 1024 * 2);
  u16* wb_c3  = (u16*)alloc(1024L * 2048 * 2);
  u16* wb_erT = (u16*)alloc(1024L * 256 * 2);
  float* dwT  = (float*)alloc(9L * 2048 * 4);
  float* qcwT = (float*)alloc(3L * 1024 * 4);
  float* kcwT = (float*)alloc(3L * 1024 * 4);
  float* bqkv = (float*)alloc(3072L * 4);
  u16* HPAD   = (u16*)alloc(2L * 1026 * 1024 * 2);         // LN2 out, zero-padded rows
  u16* LNA    = (u16*)alloc(TT * 1024 * 2);                // LN1/4/5 out
  u16* HS     = (u16*)alloc(TT * 2048 * 2);                // relu(hL)
  u16* HR     = (u16*)alloc(TT * 512 * 2);                 // relu(convR)
  u16* LN3O   = (u16*)alloc(TT * 2048 * 2);
  u16* DW9O   = (u16*)alloc(TT * 2048 * 2);
  u16* SBF    = (u16*)alloc(8L * 1024 * 1024 * 2);         // raw scaled scores bf16
  u16* qkvbuf = (u16*)alloc(TT * 3072 * 2);                // fused QKV out [2048][3072]
  u16* q2b  = (u16*)alloc(TT * 1024 * 2);
  u16* k2b  = (u16*)alloc(TT * 1024 * 2);
  u16* v2T  = (u16*)alloc(8L * 256 * 1024 * 2);
  u16* obuf = qkvbuf;   // qkv dead after qkvconv
  u16* C2O  = LN3O;     // LN3O dead after dwconv9

  // ---- weight prep + in_project (1 launch)
  Ptrs9 pj;
  pj.s[0]=glu_w; pj.d[0]=wb_glu;
  pj.s[1]=c1L_w; pj.d[1]=wb_c1L;
  pj.s[2]=c1M_pw; pj.d[2]=wb_pw;
  pj.s[3]=qw; pj.d[3]=wb_q;
  pj.s[4]=kw; pj.d[4]=wb_k;
  pj.s[5]=vw; pj.d[5]=wb_v;
  pj.s[6]=ow; pj.d[6]=wb_ow;
  pj.s[7]=c2_w; pj.d[7]=wb_c2;
  pj.s[8]=c3_w; pj.d[8]=wb_c3;
  prep_all_kernel<<<11564, 256, 0, stream>>>(pj, c1R_w, wb_c1R, er, wb_erT, c1M_dw, dwT,
                                             qcw, qcwT, kcw, kcwT, qb, kb, vb, bqkv, HPAD,
                                             x, w_in, XF);

  // ---- GLU block (fused GEMM + gate epilogue)
  ln_kernel<1024,1,0><<<2048, 256, 0, stream>>>(XF, LNA, ln1_g, ln1_b, 0, 0, nullptr);
  gemm_glu<2><<<dim3(16,32,1), 256, 0, stream>>>(LNA, wb_glu, XF);

  // ---- conv feedforward block
  ln_kernel<1024,1,0><<<2048, 256, 0, stream>>>(XF, HPAD, ln2_g, ln2_b, 2, 1, nullptr);
  gemm_c1<<<1024, 256, 0, stream>>>(HPAD, wb_c1L, wb_c1R, HS, HR);      // HS=relu(hL) || HR=relu(convR)
  ln_kernel<2048,1,1><<<2048, 256, 0, stream>>>(HS, LN3O, ln3_g, ln3_b, 0, 0, HR);
  dwconv9_kernel<<<512, 256, 0, stream>>>(LN3O, DW9O, dwT);
  gemm_bt<0,1,2,2,0,3,1,0><<<dim3(16,32,1), 256, 0, stream>>>(DW9O, wb_pw, nullptr, nullptr,
      nullptr, XF, nullptr, XF,
      2048, 1024, 2048, 0, 2048, 2048, 0, 0, 1024, 0, 0, 0,0,0,0,0,0,0,0);   // xf += pw (bf16 RMW)

  // ---- multiband attention
  ln_kernel<1024,1,0><<<2048, 256, 0, stream>>>(XF, LNA, ln4_g, ln4_b, 0, 0, nullptr);
  gemm_bt<0,1,4,2,0,2,0,0><<<dim3(48,16,1), 256, 0, stream>>>(LNA, wb_q, nullptr, nullptr,
      nullptr, qkvbuf, bqkv, nullptr,
      2048, 3072, 1024, 0, 1024, 1024, 0, 0, 3072, 0, 0, 0,0,0,0,0,0,0,0);   // fused QKV
  qkvconv_kernel<<<2560, 256, 0, stream>>>(qkvbuf, q2b, qcwT, qcb, k2b, kcwT, kcb,
                                           v2T, vcw, vcb);
  // fused scores+bias: S[z][qi][ki] = (q2.k2 + erT[qi].q2[ki]) / 32, bf16
  gemm_bt<0,1,2,2,1,3,0,1><<<dim3(16,16,8), 256, 0, stream>>>(q2b, k2b, wb_erT, q2b,
      nullptr, SBF, nullptr, nullptr,
      1024, 1024, 256, 256, 1024, 1024, 256, 1024, 1024, 0, 0,
      1048576, 256, 1048576, 256, 1048576, 256, 4194304, 1048576);
  // fused softmax + O[z] = softmax(S[z]) @ V2[z]
  fused_av<<<dim3(4,32,8), 256, 0, stream>>>(SBF, v2T, obuf);
  gemm_bt<0,1,2,2,0,3,1,0><<<dim3(16,32,1), 256, 0, stream>>>(obuf, wb_ow, nullptr, nullptr,
      nullptr, XF, ob, XF,
      2048, 1024, 1024, 0, 1024, 1024, 0, 0, 1024, 0, 0, 0,0,0,0,0,0,0,0);   // xf += o@ow^T+ob (bf16 RMW)

  // ---- squared-relu FFN
  ln_kernel<1024,1,0><<<2048, 256, 0, stream>>>(XF, LNA, ln5_g, ln5_b, 0, 0, nullptr);
  gemm_bt<2,1,4,2,0,2,0,0><<<dim3(32,16,1), 256, 0, stream>>>(LNA, wb_c2, nullptr, nullptr,
      nullptr, C2O, nullptr, nullptr,
      2048, 2048, 1024, 0, 1024, 1024, 0, 0, 2048, 0, 0, 0,0,0,0,0,0,0,0);   // relu^2 -> bf16
  gemm_bt<0,1,2,2,0,3,1,0><<<dim3(16,32,1), 256, 0, stream>>>(C2O, wb_c3, nullptr, nullptr,
      nullptr, XF, nullptr, XF,
      2048, 1024, 2048, 0, 2048, 2048, 0, 0, 1024, 0, 0, 0,0,0,0,0,0,0,0);   // xf += ffn (bf16 RMW)

  // ---- output transpose [B,1,BINS,W]
  tr_out_kernel<<<dim3(32, 32, 2), dim3(32, 8), 0, stream>>>(XF, out);
}

// Round 14
// 280.367 us; speedup vs baseline: 1.0407x; 1.0407x over previous
//
#include <hip/hip_runtime.h>

// FrameTransformer forward on MI355X.
// Dims: B=2, CH=8, BINS=1024, W=1024, FF=2048, BANDS=4, HD=256, T=B*W=2048.
// bf16 residual stream; single-barrier pipelined GEMMs (48KB LDS, 3 blocks/CU).
// Round 14: revert round-13 softmax/AV fusion (regressed); best-known config.

typedef float f32x4 __attribute__((ext_vector_type(4)));
typedef short short8 __attribute__((ext_vector_type(8)));
typedef unsigned short u16;
typedef unsigned int u32;

__device__ __forceinline__ float bf2f(u16 u){
  u32 v = ((u32)u) << 16;
  return __builtin_bit_cast(float, v);
}
__device__ __forceinline__ u16 f2bf(float f){
  u32 u = __builtin_bit_cast(u32, f);
  u32 r = (u + 0x7fffu + ((u >> 16) & 1u)) >> 16;   // RNE
  return (u16)r;
}
__device__ __forceinline__ u32 pack2(float a, float b){
  return (u32)f2bf(a) | ((u32)f2bf(b) << 16);
}
__device__ __forceinline__ void unpack8(uint4 u, float* f){
  f[0]=bf2f(u.x & 0xffffu); f[1]=bf2f(u.x >> 16);
  f[2]=bf2f(u.y & 0xffffu); f[3]=bf2f(u.y >> 16);
  f[4]=bf2f(u.z & 0xffffu); f[5]=bf2f(u.z >> 16);
  f[6]=bf2f(u.w & 0xffffu); f[7]=bf2f(u.w >> 16);
}

// async global->LDS, 16 bytes per lane
__device__ __forceinline__ void gload16(const u16* g, u16* l){
  __builtin_amdgcn_global_load_lds(
      (const __attribute__((address_space(1))) unsigned int*)g,
      (__attribute__((address_space(3))) unsigned int*)l, 16, 0, 0);
}
template<int N> __device__ __forceinline__ void waitvm(){
  asm volatile("s_waitcnt vmcnt(%0)" :: "n"(N) : "memory");
}
__device__ __forceinline__ void barrier(){ __builtin_amdgcn_s_barrier(); }

// ---------------------------------------------------------------- GEMM core
template<int ACT, int OB, int MR, int NR, int DUAL, int NBUF, int RB, int SC>
__device__ __forceinline__
void gemm_body(u16* ldsA, u16* ldsB,
               const u16* Az, const u16* Bz,
               const u16* A2, const u16* B2z,
               float* CfZ, u16* CbZ,
               const float* bias, const void* rz,
               int K, int K2, int lda, int ldb, int lda2, int ldb2, int ldc,
               int apad, int aoff, int m0, int n0)
{
  constexpr int BM = 32 * MR, BN = 32 * NR;
  constexpr int LPT = MR + NR;          // gload16 per thread per tile
  constexpr int PRE = NBUF - 1;
  const int tid = threadIdx.x;
  const int lane = tid & 63, wid = tid >> 6;
  const int wm = wid >> 1, wn = wid & 1;
  const int lr = lane & 15, lk = lane >> 4;
  const int kA = K >> 6;
  const int NT = kA + (DUAL ? (K2 >> 6) : 0);

  auto stage = [&](int buf, int s){
    #pragma unroll
    for (int i = 0; i < MR; i++){
      int ch = tid + i * 256;
      int r = ch >> 3, c = ch & 7;
      int csw = (c ^ (r & 7)) * 8;
      const u16* src;
      bool d2 = DUAL && (s >= kA);
      if (d2){
        src = A2 + (long)(m0 + r) * lda2 + (s - kA) * 64 + csw;
      } else {
        int gm = m0 + r;
        long ar = (long)gm + (long)(gm >> 10) * apad + aoff;
        src = Az + ar * lda + s * 64 + csw;
      }
      gload16(src, ldsA + buf * (BM * 64) + ch * 8);
    }
    #pragma unroll
    for (int i = 0; i < NR; i++){
      int ch = tid + i * 256;
      int r = ch >> 3, c = ch & 7;
      int csw = (c ^ (r & 7)) * 8;
      const u16* src;
      bool d2 = DUAL && (s >= kA);
      if (d2) src = B2z + (long)(n0 + r) * ldb2 + (s - kA) * 64 + csw;
      else    src = Bz  + (long)(n0 + r) * ldb  + s * 64 + csw;
      gload16(src, ldsB + buf * (BN * 64) + ch * 8);
    }
  };

  f32x4 acc[MR][NR];
  #pragma unroll
  for (int i = 0; i < MR; i++)
    #pragma unroll
    for (int j = 0; j < NR; j++) acc[i][j] = f32x4{0.f, 0.f, 0.f, 0.f};

  auto compute = [&](int cur){
    const u16* Ab = ldsA + cur * (BM * 64);
    const u16* Bb = ldsB + cur * (BN * 64);
    short8 av[2][MR], bv[2][NR];
    #pragma unroll
    for (int h = 0; h < 2; h++){
      int g = h * 4 + lk;
      #pragma unroll
      for (int i = 0; i < MR; i++){
        int row = wm * 16 * MR + i * 16 + lr;
        av[h][i] = *(const short8*)(Ab + row * 64 + ((g ^ (row & 7)) * 8));
      }
      #pragma unroll
      for (int j = 0; j < NR; j++){
        int row = wn * 16 * NR + j * 16 + lr;
        bv[h][j] = *(const short8*)(Bb + row * 64 + ((g ^ (row & 7)) * 8));
      }
    }
    #pragma unroll
    for (int h = 0; h < 2; h++)
      #pragma unroll
      for (int i = 0; i < MR; i++)
        #pragma unroll
        for (int j = 0; j < NR; j++)
          acc[i][j] = __builtin_amdgcn_mfma_f32_16x16x32_bf16(av[h][i], bv[h][j], acc[i][j], 0, 0, 0);
  };

  const int npre = NT < PRE ? NT : PRE;
  for (int p = 0; p < npre; p++) stage(p, p);
  int s = 0;
  for (; s < NT - PRE; s++){
    waitvm<(NBUF - 2) * LPT>();
    barrier();
    stage((s + PRE) % NBUF, s + PRE);
    compute(s % NBUF);
  }
  for (; s < NT; s++){
    waitvm<0>();
    barrier();
    compute(s % NBUF);
  }

  const float* rzf = (!RB) ? (const float*)rz : nullptr;
  const u16*  rzb = ( RB) ? (const u16*)rz  : nullptr;
  #pragma unroll
  for (int i = 0; i < MR; i++){
    int rowb = m0 + wm * 16 * MR + i * 16 + lk * 4;   // D: row=(lane>>4)*4+r
    #pragma unroll
    for (int j = 0; j < NR; j++){
      int colg = n0 + wn * 16 * NR + j * 16 + lr;     // D: col=lane&15
      f32x4 v = acc[i][j];
      float bvl = bias ? bias[colg] : 0.f;
      #pragma unroll
      for (int r = 0; r < 4; r++){
        long idx = (long)(rowb + r) * ldc + colg;
        float xv = v[r] + bvl;
        if constexpr (ACT == 1){ xv = fmaxf(xv, 0.f); }
        if constexpr (ACT == 2){ xv = fmaxf(xv, 0.f); xv = xv * xv; }
        if constexpr (SC){ xv *= 0.03125f; }
        if constexpr (RB){ if (rzb) xv += bf2f(rzb[idx]); }
        else             { if (rzf) xv += rzf[idx]; }
        if constexpr (OB) CbZ[idx] = f2bf(xv); else CfZ[idx] = xv;
      }
    }
  }
}

// ---------------------------------------------------------------- GEMM wrapper
template<int ACT, int OB, int MR, int NR, int DUAL, int NBUF, int RB, int SC>
__global__ __launch_bounds__(256)
void gemm_bt(const u16* __restrict__ A, const u16* __restrict__ Bw,
             const u16* __restrict__ A2, const u16* __restrict__ B2,
             float* __restrict__ Cf, u16* __restrict__ Cb,
             const float* __restrict__ bias, const void* __restrict__ resid,
             int M, int N, int K, int K2,
             int lda, int ldb, int lda2, int ldb2, int ldc,
             int apad, int aoff,
             long aZHi, long aZLo, long bZHi, long bZLo,
             long b2ZHi, long b2ZLo, long cZHi, long cZLo)
{
  constexpr int BM = 32 * MR, BN = 32 * NR;
  __shared__ __align__(16) u16 As[NBUF * BM * 64];
  __shared__ __align__(16) u16 Bs[NBUF * BN * 64];
  const int z = blockIdx.z, zh = z >> 2, zl = z & 3;
  const u16* Az = A + zh * aZHi + zl * aZLo;
  const u16* Bz = Bw + zh * bZHi + zl * bZLo;
  const u16* B2z = DUAL ? (B2 + zh * b2ZHi + zl * b2ZLo) : nullptr;
  const long coff = (long)zh * cZHi + (long)zl * cZLo;
  const int m0 = blockIdx.y * BM, n0 = blockIdx.x * BN;
  float* CfZ = Cf ? Cf + coff : nullptr;
  u16*  CbZ = Cb ? Cb + coff : nullptr;
  const void* rz = nullptr;
  if (resid) rz = RB ? (const void*)(((const u16*)resid) + coff)
                     : (const void*)(((const float*)resid) + coff);
  gemm_body<ACT,OB,MR,NR,DUAL,NBUF,RB,SC>(As, Bs, Az, Bz, A2, B2z, CfZ, CbZ,
      bias, rz, K, K2, lda, ldb, lda2, ldb2, ldc, apad, aoff, m0, n0);
}

// ---------------------------------------------------------------- fused c1L||c1R
__global__ __launch_bounds__(256)
void gemm_c1(const u16* __restrict__ HPAD, const u16* __restrict__ wbL,
             const u16* __restrict__ wbR, u16* __restrict__ HS, u16* __restrict__ HR)
{
  __shared__ __align__(16) u16 lds[24576];   // 48KB
  const int bid = blockIdx.x;
  if (bid < 512){
    const int n0 = (bid & 31) * 64, m0 = (bid >> 5) * 128;
    gemm_body<1,1,4,2,0,2,0,0>(lds, lds + 2 * 128 * 64,
        HPAD, wbL, nullptr, nullptr, nullptr, HS, nullptr, nullptr,
        1024, 0, 1024, 1024, 0, 0, 2048, 2, 1, m0, n0);
  } else {
    const int r = bid - 512;
    const int n0 = (r & 15) * 32, m0 = (r >> 4) * 64;
    gemm_body<1,1,2,1,0,4,0,0>(lds, lds + 4 * 64 * 64,
        HPAD, wbR, nullptr, nullptr, nullptr, HR, nullptr, nullptr,
        3072, 0, 1024, 3072, 0, 0, 512, 2, 0, m0, n0);
  }
}

// ---------------------------------------------------------------- fused GLU GEMM
template<int NBUF>
__global__ __launch_bounds__(256)
void gemm_glu(const u16* __restrict__ A, const u16* __restrict__ Bw,
              u16* __restrict__ XF)
{
  constexpr int LPT = 6;
  constexpr int PRE = NBUF - 1;
  constexpr int NT = 16;
  __shared__ __align__(16) u16 As[NBUF][64 * 64];
  __shared__ __align__(16) u16 Bs[NBUF][128 * 64];
  const int tid = threadIdx.x;
  const int m0 = blockIdx.y * 64, n0 = blockIdx.x * 64;
  const int lane = tid & 63, wid = tid >> 6;
  const int wm = wid >> 1, wn = wid & 1;
  const int lr = lane & 15, lk = lane >> 4;

  auto stage = [&](int buf, int s){
    #pragma unroll
    for (int i = 0; i < 2; i++){
      int ch = tid + i * 256;
      int r = ch >> 3, c = ch & 7;
      int csw = (c ^ (r & 7)) * 8;
      gload16(A + (long)(m0 + r) * 1024 + s * 64 + csw, &As[buf][ch * 8]);
    }
    #pragma unroll
    for (int i = 0; i < 4; i++){
      int ch = tid + i * 256;
      int r = ch >> 3, c = ch & 7;
      int csw = (c ^ (r & 7)) * 8;
      int grow = (r < 64) ? (n0 + r) : (1024 + n0 + r - 64);
      gload16(Bw + (long)grow * 1024 + s * 64 + csw, &Bs[buf][ch * 8]);
    }
  };

  f32x4 accv[2][2], accg[2][2];
  #pragma unroll
  for (int i = 0; i < 2; i++)
    #pragma unroll
    for (int j = 0; j < 2; j++){
      accv[i][j] = f32x4{0.f,0.f,0.f,0.f};
      accg[i][j] = f32x4{0.f,0.f,0.f,0.f};
    }

  auto compute = [&](int cur){
    const u16* Ab = &As[cur][0];
    const u16* Bb = &Bs[cur][0];
    short8 av[2][2], bvv[2][2], bvg[2][2];
    #pragma unroll
    for (int h = 0; h < 2; h++){
      int g = h * 4 + lk;
      #pragma unroll
      for (int i = 0; i < 2; i++){
        int row = wm * 32 + i * 16 + lr;
        av[h][i] = *(const short8*)(Ab + row * 64 + ((g ^ (row & 7)) * 8));
      }
      #pragma unroll
      for (int j = 0; j < 2; j++){
        int row = wn * 32 + j * 16 + lr;
        bvv[h][j] = *(const short8*)(Bb + row * 64 + ((g ^ (row & 7)) * 8));
        int rowg = 64 + row;
        bvg[h][j] = *(const short8*)(Bb + rowg * 64 + ((g ^ (rowg & 7)) * 8));
      }
    }
    #pragma unroll
    for (int h = 0; h < 2; h++)
      #pragma unroll
      for (int i = 0; i < 2; i++)
        #pragma unroll
        for (int j = 0; j < 2; j++){
          accv[i][j] = __builtin_amdgcn_mfma_f32_16x16x32_bf16(av[h][i], bvv[h][j], accv[i][j], 0, 0, 0);
          accg[i][j] = __builtin_amdgcn_mfma_f32_16x16x32_bf16(av[h][i], bvg[h][j], accg[i][j], 0, 0, 0);
        }
  };

  const int npre = NT < PRE ? NT : PRE;
  for (int p = 0; p < npre; p++) stage(p, p);
  int s = 0;
  for (; s < NT - PRE; s++){
    waitvm<(NBUF - 2) * LPT>();
    barrier();
    stage((s + PRE) % NBUF, s + PRE);
    compute(s % NBUF);
  }
  for (; s < NT; s++){
    waitvm<0>();
    barrier();
    compute(s % NBUF);
  }

  #pragma unroll
  for (int i = 0; i < 2; i++){
    int rowb = m0 + wm * 32 + i * 16 + lk * 4;
    #pragma unroll
    for (int j = 0; j < 2; j++){
      int colg = n0 + wn * 32 + j * 16 + lr;
      #pragma unroll
      for (int r = 0; r < 4; r++){
        long idx = (long)(rowb + r) * 1024 + colg;
        float g = accg[i][j][r];
        float nv = bf2f(XF[idx]) + accv[i][j][r] / (1.f + __expf(-g));
        XF[idx] = f2bf(nv);
      }
    }
  }
}

// ---------------------------------------------------------------- LayerNorm
template<int NC, int INBF, int ADDHR>
__global__ __launch_bounds__(256)
void ln_kernel(const void* __restrict__ in, u16* __restrict__ out,
               const float* __restrict__ gg, const float* __restrict__ bb,
               int rowpad, int rowadd, const u16* __restrict__ addp)
{
  constexpr int PER = NC / 256;
  const int row = blockIdx.x;
  const int tid = threadIdx.x;
  float v[PER];
  if constexpr (INBF){
    const u16* x = ((const u16*)in) + (long)row * NC + tid * PER;
    if constexpr (PER == 4){
      uint2 u = *(const uint2*)x;
      v[0]=bf2f(u.x & 0xffffu); v[1]=bf2f(u.x >> 16);
      v[2]=bf2f(u.y & 0xffffu); v[3]=bf2f(u.y >> 16);
    } else {
      #pragma unroll
      for (int i = 0; i < PER; i += 8){
        uint4 u = *(const uint4*)(x + i);
        unpack8(u, &v[i]);
      }
    }
  } else {
    const float* x = ((const float*)in) + (long)row * NC + tid * PER;
    #pragma unroll
    for (int i = 0; i < PER; i += 4){
      f32x4 t = *(const f32x4*)(x + i);
      v[i] = t.x; v[i+1] = t.y; v[i+2] = t.z; v[i+3] = t.w;
    }
  }
  if constexpr (ADDHR){
    const int c0i = tid * PER;            // PER==8 here
    if (c0i < 512){
      uint4 u = *(const uint4*)(addp + (long)row * 512 + c0i);
      float a8[8]; unpack8(u, a8);
      #pragma unroll
      for (int i = 0; i < 8; i++) v[i] += a8[i];
    }
  }
  float s = 0.f, sq = 0.f;
  #pragma unroll
  for (int i = 0; i < PER; i++){ s += v[i]; sq += v[i] * v[i]; }
  #pragma unroll
  for (int o = 32; o; o >>= 1){ s += __shfl_xor(s, o); sq += __shfl_xor(sq, o); }
  __shared__ float as_[4], aq_[4];
  const int wv = tid >> 6;
  if ((tid & 63) == 0){ as_[wv] = s; aq_[wv] = sq; }
  __syncthreads();
  s  = as_[0] + as_[1] + as_[2] + as_[3];
  sq = aq_[0] + aq_[1] + aq_[2] + aq_[3];
  const float mean = s * (1.f / NC);
  const float var  = sq * (1.f / NC) - mean * mean;
  const float rs = rsqrtf(var + 1e-5f);
  const long orow = (long)row + (long)(row >> 10) * rowpad + rowadd;
  u16* op = out + orow * NC + tid * PER;
  u32 word[PER / 2];
  #pragma unroll
  for (int i = 0; i < PER; i += 2){
    int c = tid * PER + i;
    float y0 = (v[i]   - mean) * rs * gg[c]   + bb[c];
    float y1 = (v[i+1] - mean) * rs * gg[c+1] + bb[c+1];
    word[i / 2] = pack2(y0, y1);
  }
  if constexpr (PER == 4) *(uint2*)op = *(uint2*)word;
  else                    *(uint4*)op = *(uint4*)word;
}

// ---------------------------------------------------------------- small kernels
// XF bf16 [b*1024+w][f] -> out fp32 [b][1][f][w]
__global__ __launch_bounds__(256)
void tr_out_kernel(const u16* __restrict__ xf, float* __restrict__ out)
{
  __shared__ float tile[32][33];
  const int b = blockIdx.z, f0 = blockIdx.x * 32, w0 = blockIdx.y * 32;
  const int tx = threadIdx.x, ty = threadIdx.y;
  #pragma unroll
  for (int i = 0; i < 4; i++)
    tile[ty + i * 8][tx] = bf2f(xf[((long)(b * 1024 + w0 + ty + i * 8)) * 1024 + f0 + tx]);
  __syncthreads();
  #pragma unroll
  for (int i = 0; i < 4; i++)
    out[((long)(b * 1024 + f0 + ty + i * 8)) * 1024 + w0 + tx] = tile[tx][ty + i * 8];
}

// depthwise conv k=9: dwT[9][2048]; 8ch x 4tok per thread, sliding window.
__global__ __launch_bounds__(256)
void dwconv9_kernel(const u16* __restrict__ in, u16* __restrict__ out,
                    const float* __restrict__ dwT)
{
  const int id = blockIdx.x * 256 + threadIdx.x;   // 512 blocks
  const int cg = id & 255;
  const int tg = id >> 8;
  const int c0 = cg * 8;
  const int t0 = tg * 4;
  const int b = t0 >> 10;
  const int w0 = t0 & 1023;
  const u16* bin = in + ((long)b << 10) * 2048 + c0;
  float wt[9][8];
  #pragma unroll
  for (int j = 0; j < 9; j++){
    f32x4 lo = *(const f32x4*)(dwT + j * 2048 + c0);
    f32x4 hi = *(const f32x4*)(dwT + j * 2048 + c0 + 4);
    wt[j][0]=lo.x; wt[j][1]=lo.y; wt[j][2]=lo.z; wt[j][3]=lo.w;
    wt[j][4]=hi.x; wt[j][5]=hi.y; wt[j][6]=hi.z; wt[j][7]=hi.w;
  }
  float win[9][8];
  #pragma unroll
  for (int r = 0; r < 9; r++){
    int wr = w0 - 4 + r;
    if (wr >= 0 && wr < 1024){
      uint4 u = *(const uint4*)(bin + (long)wr * 2048);
      unpack8(u, win[r]);
    } else {
      #pragma unroll
      for (int i = 0; i < 8; i++) win[r][i] = 0.f;
    }
  }
  #pragma unroll
  for (int s = 0; s < 4; s++){
    float acc[8] = {0,0,0,0,0,0,0,0};
    #pragma unroll
    for (int j = 0; j < 9; j++)
      #pragma unroll
      for (int i = 0; i < 8; i++)
        acc[i] += win[(s + j) % 9][i] * wt[j][i];
    uint4 o;
    o.x = pack2(acc[0], acc[1]); o.y = pack2(acc[2], acc[3]);
    o.z = pack2(acc[4], acc[5]); o.w = pack2(acc[6], acc[7]);
    *(uint4*)(out + (long)(t0 + s) * 2048 + c0) = o;
    if (s < 3){
      int wr = w0 + s + 5;
      if (wr < 1024){
        uint4 u = *(const uint4*)(bin + (long)wr * 2048);
        unpack8(u, win[s % 9]);
      } else {
        #pragma unroll
        for (int i = 0; i < 8; i++) win[s % 9][i] = 0.f;
      }
    }
  }
}

// merged q/k depthwise conv3 (bid<512) + v conv3-transpose (bid>=512)
__global__ __launch_bounds__(256)
void qkvconv_kernel(const u16* __restrict__ qkv,
                    u16* __restrict__ q2b, const float* __restrict__ qwT, const float* __restrict__ qbb,
                    u16* __restrict__ k2b, const float* __restrict__ kwT, const float* __restrict__ kbb,
                    u16* __restrict__ v2T, const float* __restrict__ vcw, const float* __restrict__ vcb)
{
  __shared__ float ins[34][33];
  __shared__ float outs[32][33];
  const int bid = blockIdx.x;
  const int tid = threadIdx.x;
  if (bid < 512){
    const int sel = bid >> 8;
    const u16* in  = qkv + sel * 1024;
    u16* out       = sel ? k2b : q2b;
    const float* wT = sel ? kwT : qwT;
    const float* bp = sel ? kbb : qbb;
    const int id = (bid & 255) * 256 + tid;
    const int cg = id & 127;
    const int tg = id >> 7;
    const int c0 = cg * 8;
    const int t0 = tg * 4;
    const int b = t0 >> 10;
    const int w0 = t0 & 1023;
    const u16* bin = in + ((long)b << 10) * 3072 + c0;
    float wt[3][8], bias[8];
    #pragma unroll
    for (int j = 0; j < 3; j++){
      f32x4 lo = *(const f32x4*)(wT + j * 1024 + c0);
      f32x4 hi = *(const f32x4*)(wT + j * 1024 + c0 + 4);
      wt[j][0]=lo.x; wt[j][1]=lo.y; wt[j][2]=lo.z; wt[j][3]=lo.w;
      wt[j][4]=hi.x; wt[j][5]=hi.y; wt[j][6]=hi.z; wt[j][7]=hi.w;
    }
    {
      f32x4 lo = *(const f32x4*)(bp + c0);
      f32x4 hi = *(const f32x4*)(bp + c0 + 4);
      bias[0]=lo.x; bias[1]=lo.y; bias[2]=lo.z; bias[3]=lo.w;
      bias[4]=hi.x; bias[5]=hi.y; bias[6]=hi.z; bias[7]=hi.w;
    }
    float win[3][8];
    #pragma unroll
    for (int r = 0; r < 3; r++){
      int wr = w0 - 1 + r;
      if (wr >= 0 && wr < 1024){
        uint4 u = *(const uint4*)(bin + (long)wr * 3072);
        unpack8(u, win[r]);
      } else {
        #pragma unroll
        for (int i = 0; i < 8; i++) win[r][i] = 0.f;
      }
    }
    #pragma unroll
    for (int s = 0; s < 4; s++){
      float acc[8];
      #pragma unroll
      for (int i = 0; i < 8; i++) acc[i] = bias[i];
      #pragma unroll
      for (int j = 0; j < 3; j++)
        #pragma unroll
        for (int i = 0; i < 8; i++)
          acc[i] += win[(s + j) % 3][i] * wt[j][i];
      uint4 o;
      o.x = pack2(acc[0], acc[1]); o.y = pack2(acc[2], acc[3]);
      o.z = pack2(acc[4], acc[5]); o.w = pack2(acc[6], acc[7]);
      *(uint4*)(out + (long)(t0 + s) * 1024 + c0) = o;
      if (s < 3){
        int wr = w0 + s + 2;
        if (wr < 1024){
          uint4 u = *(const uint4*)(bin + (long)wr * 3072);
          unpack8(u, win[s % 3]);
        } else {
          #pragma unroll
          for (int i = 0; i < 8; i++) win[s % 3][i] = 0.f;
        }
      }
    }
  } else {
    const int vb = bid - 512;                        // 2048 blocks
    const int b = vb >> 10;
    const int rem = vb & 1023;
    const int w0 = (rem & 31) * 32, c0 = (rem >> 5) * 32;
    const int tx = tid & 31, ty = tid >> 5;
    const u16* in = qkv + 2048;
    for (int r = ty; r < 34; r += 8){
      int w = w0 - 1 + r;
      ins[r][tx] = (w >= 0 && w < 1024) ? bf2f(in[((long)(b * 1024 + w)) * 3072 + c0 + tx]) : 0.f;
    }
    __syncthreads();
    const float wt0 = vcw[(c0 + tx) * 3 + 0], wt1 = vcw[(c0 + tx) * 3 + 1], wt2 = vcw[(c0 + tx) * 3 + 2];
    const float bb = vcb[c0 + tx];
    #pragma unroll
    for (int i = 0; i < 4; i++){
      int wl = ty + i * 8;
      outs[wl][tx] = ins[wl][tx] * wt0 + ins[wl + 1][tx] * wt1 + ins[wl + 2][tx] * wt2 + bb;
    }
    __syncthreads();
    #pragma unroll
    for (int i = 0; i < 4; i++){
      int cl = ty + i * 8;
      int c = c0 + cl; int n = c >> 8; int h = c & 255;
      v2T[((long)((b * 4 + n) * 256 + h)) * 1024 + w0 + tx] = f2bf(outs[tx][cl]);
    }
  }
}

// softmax over 1024-wide rows, bf16 in-place; ONE WAVE PER ROW (no LDS/barriers)
__global__ __launch_bounds__(256)
void softmax_kernel(u16* __restrict__ buf)
{
  const long row = (long)blockIdx.x * 4 + (threadIdx.x >> 6);
  const int lane = threadIdx.x & 63;
  u16* p = buf + row * 1024 + lane * 16;
  uint4 a = *(const uint4*)p;
  uint4 b = *(const uint4*)(p + 8);
  float v[16];
  unpack8(a, v); unpack8(b, v + 8);
  float m = v[0];
  #pragma unroll
  for (int i = 1; i < 16; i++) m = fmaxf(m, v[i]);
  #pragma unroll
  for (int o = 32; o; o >>= 1) m = fmaxf(m, __shfl_xor(m, o));
  float e[16];
  float s = 0.f;
  #pragma unroll
  for (int i = 0; i < 16; i++){ e[i] = __expf(v[i] - m); s += e[i]; }
  #pragma unroll
  for (int o = 32; o; o >>= 1) s += __shfl_xor(s, o);
  const float inv = 1.f / s;
  u32 w[8];
  #pragma unroll
  for (int i = 0; i < 16; i += 2) w[i / 2] = pack2(e[i] * inv, e[i + 1] * inv);
  *(uint4*)p = *(uint4*)&w[0];
  *(uint4*)(p + 8) = *(uint4*)&w[4];
}

// ---------------------------------------------------------------- prep (merged, vectorized)
struct Ptrs9 { const float* s[9]; u16* d[9]; };

__global__ __launch_bounds__(256)
void prep_all_kernel(Ptrs9 p,
                     const float* __restrict__ c1R_w, u16* __restrict__ wb_c1R,
                     const float* __restrict__ er, u16* __restrict__ wb_erT,
                     const float* __restrict__ c1M_dw, float* __restrict__ dwT,
                     const float* __restrict__ qcw, float* __restrict__ qcwT,
                     const float* __restrict__ kcw, float* __restrict__ kcwT,
                     const float* __restrict__ qb, const float* __restrict__ kb,
                     const float* __restrict__ vb, float* __restrict__ bqkv,
                     u16* __restrict__ hpad,
                     const float* __restrict__ x, const float* __restrict__ w_in,
                     u16* __restrict__ XF)
{
  __shared__ float tile[32][33];
  const int tid = threadIdx.x;
  const int bid = blockIdx.x;
  if (bid < 7168){
    int job, base;
    if      (bid < 1024){ job = 0; base = 0; }
    else if (bid < 2048){ job = 1; base = 1024; }
    else if (bid < 3072){ job = 2; base = 2048; }
    else if (bid < 3584){ job = 3; base = 3072; }
    else if (bid < 4096){ job = 4; base = 3584; }
    else if (bid < 4608){ job = 5; base = 4096; }
    else if (bid < 5120){ job = 6; base = 4608; }
    else if (bid < 6144){ job = 7; base = 5120; }
    else                { job = 8; base = 6144; }
    long off = ((long)(bid - base) * 256 + tid) * 8;
    const float* src = p.s[job] + off;
    f32x4 va = *(const f32x4*)src;
    f32x4 vb4 = *(const f32x4*)(src + 4);
    uint4 o;
    o.x = pack2(va.x, va.y); o.y = pack2(va.z, va.w);
    o.z = pack2(vb4.x, vb4.y); o.w = pack2(vb4.z, vb4.w);
    *(uint4*)(p.d[job] + off) = o;
    return;
  }
  const int b2 = bid - 7168;   // 0..4395
  if (b2 < 2048){
    int t = b2 * 256 + tid;
    int oc = t >> 10, ic = t & 1023;
    const float* src = c1R_w + (long)oc * 3072 + ic * 3;
    float r0 = src[0], r1 = src[1], r2 = src[2];
    u16* dst = wb_c1R + (long)oc * 3072 + ic;
    dst[0]    = f2bf(r0);
    dst[1024] = f2bf(r1);
    dst[2048] = f2bf(r2);
  } else if (b2 < 2304){
    int r = b2 - 2048;
    int h0 = (r & 7) * 32, q0 = (r >> 3) * 32;
    int tx = tid & 31, ty = tid >> 5;
    #pragma unroll
    for (int i = 0; i < 4; i++)
      tile[ty + i * 8][tx] = er[(long)(h0 + ty + i * 8) * 1024 + q0 + tx];
    __syncthreads();
    #pragma unroll
    for (int i = 0; i < 4; i++)
      wb_erT[(long)(q0 + ty + i * 8) * 256 + h0 + tx] = f2bf(tile[tx][ty + i * 8]);
  } else if (b2 < 2312){
    int c = (b2 - 2304) * 256 + tid;
    const float* src = c1M_dw + (long)c * 9;
    #pragma unroll
    for (int j = 0; j < 9; j++) dwT[j * 2048 + c] = src[j];
  } else if (b2 < 2316){
    int c = (b2 - 2312) * 256 + tid;
    const float* src = qcw + (long)c * 3;
    #pragma unroll
    for (int j = 0; j < 3; j++) qcwT[j * 1024 + c] = src[j];
  } else if (b2 < 2320){
    int c = (b2 - 2316) * 256 + tid;
    const float* src = kcw + (long)c * 3;
    #pragma unroll
    for (int j = 0; j < 3; j++) kcwT[j * 1024 + c] = src[j];
  } else if (b2 < 2332){
    int id = (b2 - 2320) * 256 + tid;
    bqkv[id] = (id < 1024) ? qb[id] : (id < 2048) ? kb[id - 1024] : vb[id - 2048];
  } else if (b2 < 2348){
    int id = (b2 - 2332) * 256 + tid;
    int r = id >> 10; int c = id & 1023;
    int b = r >> 1; int edge = r & 1;
    long row = (long)b * 1026 + (edge ? 1025 : 0);
    hpad[row * 1024 + c] = 0;
  } else {
    const int vb4 = b2 - 2348;
    const int b = vb4 >> 10;
    const int rem = vb4 & 1023;
    const int f0 = (rem & 31) * 32, w0 = (rem >> 5) * 32;
    const int tx = tid & 7, ty = tid >> 3;
    float wr[8];
    #pragma unroll
    for (int c = 0; c < 8; c++) wr[c] = w_in[c];
    f32x4 acc = f32x4{0.f, 0.f, 0.f, 0.f};
    #pragma unroll
    for (int c = 0; c < 8; c++){
      f32x4 xv = *(const f32x4*)(x + (((long)(b * 8 + c)) * 1024 + f0 + ty) * 1024 + w0 + tx * 4);
      acc += wr[c] * xv;
    }
    tile[ty][tx * 4 + 0] = acc.x;
    tile[ty][tx * 4 + 1] = acc.y;
    tile[ty][tx * 4 + 2] = acc.z;
    tile[ty][tx * 4 + 3] = acc.w;
    __syncthreads();
    const int wl = tid >> 3, fseg = (tid & 7) * 4;
    uint2 o;
    o.x = pack2(tile[fseg + 0][wl], tile[fseg + 1][wl]);
    o.y = pack2(tile[fseg + 2][wl], tile[fseg + 3][wl]);
    *(uint2*)(XF + ((long)(b * 1024 + w0 + wl)) * 1024 + f0 + fseg) = o;
  }
}

// ---------------------------------------------------------------- launch
extern "C" void kernel_launch(void* const* d_in, const int* in_sizes, int n_in,
                              void* d_out, int out_size, void* d_ws, size_t ws_size,
                              hipStream_t stream)
{
  (void)in_sizes; (void)n_in; (void)out_size; (void)ws_size;
  const float* x     = (const float*)d_in[0];
  const float* w_in  = (const float*)d_in[1];
  const float* ln1_g = (const float*)d_in[2];
  const float* ln1_b = (const float*)d_in[3];
  const float* glu_w = (const float*)d_in[4];
  const float* ln2_g = (const float*)d_in[5];
  const float* ln2_b = (const float*)d_in[6];
  const float* c1L_w = (const float*)d_in[7];
  const float* c1R_w = (const float*)d_in[8];
  const float* ln3_g = (const float*)d_in[9];
  const float* ln3_b = (const float*)d_in[10];
  const float* c1M_dw= (const float*)d_in[11];
  const float* c1M_pw= (const float*)d_in[12];
  const float* ln4_g = (const float*)d_in[13];
  const float* ln4_b = (const float*)d_in[14];
  const float* qw  = (const float*)d_in[15];
  const float* qb  = (const float*)d_in[16];
  const float* qcw = (const float*)d_in[17];
  const float* qcb = (const float*)d_in[18];
  const float* kw  = (const float*)d_in[19];
  const float* kb  = (const float*)d_in[20];
  const float* kcw = (const float*)d_in[21];
  const float* kcb = (const float*)d_in[22];
  const float* vw  = (const float*)d_in[23];
  const float* vb  = (const float*)d_in[24];
  const float* vcw = (const float*)d_in[25];
  const float* vcb = (const float*)d_in[26];
  const float* ow  = (const float*)d_in[27];
  const float* ob  = (const float*)d_in[28];
  const float* er  = (const float*)d_in[29];
  const float* ln5_g = (const float*)d_in[30];
  const float* ln5_b = (const float*)d_in[31];
  const float* c2_w  = (const float*)d_in[32];
  const float* c3_w  = (const float*)d_in[33];
  float* out = (float*)d_out;

  const long TT = 2048;   // B*W tokens
  char* wsb = (char*)d_ws;
  size_t off = 0;
  auto alloc = [&](size_t bytes) -> char* {
    char* p = wsb + off;
    off = (off + bytes + 255) & ~(size_t)255;
    return p;
  };
  u16* XF     = (u16*)alloc(TT * 1024 * 2);                // bf16 residual stream
  u16* wb_glu = (u16*)alloc(2048L * 1024 * 2);
  u16* wb_c1L = (u16*)alloc(2048L * 1024 * 2);
  u16* wb_c1R = (u16*)alloc(512L * 3072 * 2);
  u16* wb_pw  = (u16*)alloc(1024L * 2048 * 2);
  u16* wb_q   = (u16*)alloc(1024L * 1024 * 2);             // contiguous with k,v
  u16* wb_k   = (u16*)alloc(1024L * 1024 * 2);
  u16* wb_v   = (u16*)alloc(1024L * 1024 * 2);
  u16* wb_ow  = (u16*)alloc(1024L * 1024 * 2);
  u16* wb_c2  = (u16*)alloc(2048L * 1024 * 2);
  u16* wb_c3  = (u16*)alloc(1024L * 2048 * 2);
  u16* wb_erT = (u16*)alloc(1024L * 256 * 2);
  float* dwT  = (float*)alloc(9L * 2048 * 4);
  float* qcwT = (float*)alloc(3L * 1024 * 4);
  float* kcwT = (float*)alloc(3L * 1024 * 4);
  float* bqkv = (float*)alloc(3072L * 4);
  u16* HPAD   = (u16*)alloc(2L * 1026 * 1024 * 2);         // LN2 out, zero-padded rows
  u16* LNA    = (u16*)alloc(TT * 1024 * 2);                // LN1/4/5 out
  u16* HS     = (u16*)alloc(TT * 2048 * 2);                // relu(hL)
  u16* HR     = (u16*)alloc(TT * 512 * 2);                 // relu(convR)
  u16* LN3O   = (u16*)alloc(TT * 2048 * 2);
  u16* DW9O   = (u16*)alloc(TT * 2048 * 2);
  u16* SBF    = (u16*)alloc(8L * 1024 * 1024 * 2);         // scores bf16 (softmax in-place)
  u16* qkvbuf = (u16*)alloc(TT * 3072 * 2);                // fused QKV out [2048][3072]
  u16* q2b  = (u16*)alloc(TT * 1024 * 2);
  u16* k2b  = (u16*)alloc(TT * 1024 * 2);
  u16* v2T  = (u16*)alloc(8L * 256 * 1024 * 2);
  u16* obuf = qkvbuf;   // qkv dead after qkvconv
  u16* C2O  = LN3O;     // LN3O dead after dwconv9

  // ---- weight prep + in_project (1 launch)
  Ptrs9 pj;
  pj.s[0]=glu_w; pj.d[0]=wb_glu;
  pj.s[1]=c1L_w; pj.d[1]=wb_c1L;
  pj.s[2]=c1M_pw; pj.d[2]=wb_pw;
  pj.s[3]=qw; pj.d[3]=wb_q;
  pj.s[4]=kw; pj.d[4]=wb_k;
  pj.s[5]=vw; pj.d[5]=wb_v;
  pj.s[6]=ow; pj.d[6]=wb_ow;
  pj.s[7]=c2_w; pj.d[7]=wb_c2;
  pj.s[8]=c3_w; pj.d[8]=wb_c3;
  prep_all_kernel<<<11564, 256, 0, stream>>>(pj, c1R_w, wb_c1R, er, wb_erT, c1M_dw, dwT,
                                             qcw, qcwT, kcw, kcwT, qb, kb, vb, bqkv, HPAD,
                                             x, w_in, XF);

  // ---- GLU block (fused GEMM + gate epilogue)
  ln_kernel<1024,1,0><<<2048, 256, 0, stream>>>(XF, LNA, ln1_g, ln1_b, 0, 0, nullptr);
  gemm_glu<2><<<dim3(16,32,1), 256, 0, stream>>>(LNA, wb_glu, XF);

  // ---- conv feedforward block
  ln_kernel<1024,1,0><<<2048, 256, 0, stream>>>(XF, HPAD, ln2_g, ln2_b, 2, 1, nullptr);
  gemm_c1<<<1024, 256, 0, stream>>>(HPAD, wb_c1L, wb_c1R, HS, HR);      // HS=relu(hL) || HR=relu(convR)
  ln_kernel<2048,1,1><<<2048, 256, 0, stream>>>(HS, LN3O, ln3_g, ln3_b, 0, 0, HR);
  dwconv9_kernel<<<512, 256, 0, stream>>>(LN3O, DW9O, dwT);
  gemm_bt<0,1,2,2,0,3,1,0><<<dim3(16,32,1), 256, 0, stream>>>(DW9O, wb_pw, nullptr, nullptr,
      nullptr, XF, nullptr, XF,
      2048, 1024, 2048, 0, 2048, 2048, 0, 0, 1024, 0, 0, 0,0,0,0,0,0,0,0);   // xf += pw (bf16 RMW)

  // ---- multiband attention
  ln_kernel<1024,1,0><<<2048, 256, 0, stream>>>(XF, LNA, ln4_g, ln4_b, 0, 0, nullptr);
  gemm_bt<0,1,4,2,0,2,0,0><<<dim3(48,16,1), 256, 0, stream>>>(LNA, wb_q, nullptr, nullptr,
      nullptr, qkvbuf, bqkv, nullptr,
      2048, 3072, 1024, 0, 1024, 1024, 0, 0, 3072, 0, 0, 0,0,0,0,0,0,0,0);   // fused QKV
  qkvconv_kernel<<<2560, 256, 0, stream>>>(qkvbuf, q2b, qcwT, qcb, k2b, kcwT, kcb,
                                           v2T, vcw, vcb);
  // fused scores+bias: S[z][qi][ki] = (q2.k2 + erT[qi].q2[ki]) / 32, bf16
  gemm_bt<0,1,2,2,1,3,0,1><<<dim3(16,16,8), 256, 0, stream>>>(q2b, k2b, wb_erT, q2b,
      nullptr, SBF, nullptr, nullptr,
      1024, 1024, 256, 256, 1024, 1024, 256, 1024, 1024, 0, 0,
      1048576, 256, 1048576, 256, 1048576, 256, 4194304, 1048576);
  softmax_kernel<<<2048, 256, 0, stream>>>(SBF);
  // O[z] = A[z] @ V2[z]
  gemm_bt<0,1,1,2,0,4,0,0><<<dim3(4,32,8), 256, 0, stream>>>(SBF, v2T, nullptr, nullptr,
      nullptr, obuf, nullptr, nullptr,
      1024, 256, 1024, 0, 1024, 1024, 0, 0, 1024, 0, 0,
      4194304, 1048576, 1048576, 262144, 0, 0, 1048576, 256);
  gemm_bt<0,1,2,2,0,3,1,0><<<dim3(16,32,1), 256, 0, stream>>>(obuf, wb_ow, nullptr, nullptr,
      nullptr, XF, ob, XF,
      2048, 1024, 1024, 0, 1024, 1024, 0, 0, 1024, 0, 0, 0,0,0,0,0,0,0,0);   // xf += o@ow^T+ob (bf16 RMW)

  // ---- squared-relu FFN
  ln_kernel<1024,1,0><<<2048, 256, 0, stream>>>(XF, LNA, ln5_g, ln5_b, 0, 0, nullptr);
  gemm_bt<2,1,4,2,0,2,0,0><<<dim3(32,16,1), 256, 0, stream>>>(LNA, wb_c2, nullptr, nullptr,
      nullptr, C2O, nullptr, nullptr,
      2048, 2048, 1024, 0, 1024, 1024, 0, 0, 2048, 0, 0, 0,0,0,0,0,0,0,0);   // relu^2 -> bf16
  gemm_bt<0,1,2,2,0,3,1,0><<<dim3(16,32,1), 256, 0, stream>>>(C2O, wb_c3, nullptr, nullptr,
      nullptr, XF, nullptr, XF,
      2048, 1024, 2048, 0, 2048, 2048, 0, 0, 1024, 0, 0, 0,0,0,0,0,0,0,0);   // xf += ffn (bf16 RMW)

  // ---- output transpose [B,1,BINS,W]
  tr_out_kernel<<<dim3(32, 32, 2), dim3(32, 8), 0, stream>>>(XF, out);
}